// Round 6
// baseline (292.485 us; speedup 1.0000x reference)
//
#include <hip/hip_runtime.h>
#include <math.h>

// S3RNN: tokens -> per-token unit quaternion (64-entry table) -> chunked
// parallel scan of normalized quaternion products -> 4->64->64 gelu head.
// PROVEN BY BISECTION (R0-R5): inputs are float32, d_out is FLOAT32
// (33554432 f32 logits, then 524288 f32 sigmas). The harness's "(bf16)"
// label is comparison mode only.
namespace {
constexpr int kB   = 256;
constexpr int kT   = 2048;
constexpr int kH   = 64;
constexpr int kV   = 64;
constexpr int kNC  = 64;          // chunks per row
constexpr int kCL  = kT / kNC;    // 32 steps per chunk
constexpr int kBT  = kB * kT;     // 524288
constexpr int kEOS = 2;
constexpr int kNChunksTotal = kB * kNC;  // 16384
}

__device__ __forceinline__ float gelu_exact(float x) {
    return 0.5f * x * (1.0f + erff(x * 0.70710678118654752440f));
}

struct Quat { float w, x, y, z; };

__device__ __forceinline__ Quat qmul(Quat a, Quat b) {
    Quat r;
    r.w = a.w*b.w - a.x*b.x - a.y*b.y - a.z*b.z;
    r.x = a.w*b.x + a.x*b.w + a.y*b.z - a.z*b.y;
    r.y = a.w*b.y - a.x*b.z + a.y*b.w + a.z*b.x;
    r.z = a.w*b.z + a.x*b.y - a.y*b.x + a.z*b.w;
    return r;
}

__device__ __forceinline__ Quat qnorm(Quat a) {
    float n2 = a.w*a.w + a.x*a.x + a.y*a.y + a.z*a.z;
    float n  = fmaxf(sqrtf(n2), 1e-12f);
    float inv = 1.0f / n;
    return Quat{a.w*inv, a.x*inv, a.y*inv, a.z*inv};
}

// ---- Scratch-in-out addressing (f32 layout) ----
// Slot t = f32 elements [t*64, (t+1)*64) = bytes [t*256, t*256+256).
// Staging (overwritten by k_head's full-slot logit write):
//   byte +0  : C_t float4 (w,x,y,z)
//   byte +16 : chunk_prod[t]  (t < 16384 only)
//   byte +32 : prefix[t]      (t < 16384 only)
__device__ __forceinline__ float4* slotC(float* out, int t) {
    return reinterpret_cast<float4*>(reinterpret_cast<char*>(out) + (size_t)t * 256);
}
__device__ __forceinline__ float4* slotCP(float* out, int i) {
    return reinterpret_cast<float4*>(reinterpret_cast<char*>(out) + (size_t)i * 256 + 16);
}
__device__ __forceinline__ float4* slotPF(float* out, int i) {
    return reinterpret_cast<float4*>(reinterpret_cast<char*>(out) + (size_t)i * 256 + 32);
}

// Token -> unit quaternion table in LDS. Needs >=64 threads.
__device__ void build_gtable(const float* __restrict__ eW1, const float* __restrict__ eb1,
                             const float* __restrict__ eW2, const float* __restrict__ eb2,
                             float4* gt) {
    int tid = threadIdx.x;
    if (tid < kV) {
        float a0 = 0.f, a1 = 0.f, a2 = 0.f, a3 = 0.f;
        const float* row = eW1 + tid * kH;
        for (int k = 0; k < kH; ++k) {
            float h = gelu_exact(row[k] + eb1[k]);
            a0 += h * eW2[k*4+0];
            a1 += h * eW2[k*4+1];
            a2 += h * eW2[k*4+2];
            a3 += h * eW2[k*4+3];
        }
        Quat g{a0 + eb2[0], a1 + eb2[1], a2 + eb2[2], a3 + eb2[3]};
        g = qnorm(g);
        if (tid == kEOS) g = Quat{1.f, 0.f, 0.f, 0.f};
        gt[tid] = make_float4(g.w, g.x, g.y, g.z);
    }
    __syncthreads();
}

// Phase 1: per-(row,chunk) product of 32 g's (normalized each step, like ref).
__global__ void k_chunkprod(const int* __restrict__ tokens,
                            const float* __restrict__ eW1, const float* __restrict__ eb1,
                            const float* __restrict__ eW2, const float* __restrict__ eb2,
                            float* __restrict__ out) {
    __shared__ float4 gt[kV];
    build_gtable(eW1, eb1, eW2, eb2, gt);
    int gid = blockIdx.x * blockDim.x + threadIdx.x;   // 0 .. 16383
    int b = gid / kNC, c = gid % kNC;
    const int* tp = tokens + b * kT + c * kCL;
    Quat Q{1.f, 0.f, 0.f, 0.f};
    #pragma unroll 4
    for (int i = 0; i < kCL; ++i) {
        float4 g4 = gt[tp[i]];
        Q = qnorm(qmul(Q, Quat{g4.x, g4.y, g4.z, g4.w}));
    }
    *slotCP(out, gid) = make_float4(Q.w, Q.x, Q.y, Q.z);
}

// Phase 2: per-row exclusive prefix over 64 chunk products (32 rows/block).
__global__ void k_prefix(float* __restrict__ out) {
    __shared__ float4 lds[32 * kNC];   // 32 KB
    int r0 = blockIdx.x * 32;
    for (int i = threadIdx.x; i < 32 * kNC; i += blockDim.x)
        lds[i] = *slotCP(out, r0 * kNC + i);
    __syncthreads();
    int tid = threadIdx.x;
    if (tid < 32) {
        int row = r0 + tid;
        Quat P{1.f, 0.f, 0.f, 0.f};
        for (int c = 0; c < kNC; ++c) {
            *slotPF(out, row * kNC + c) = make_float4(P.w, P.x, P.y, P.z);
            float4 q4 = lds[tid * kNC + c];
            P = qnorm(qmul(P, Quat{q4.x, q4.y, q4.z, q4.w}));
        }
    }
}

// Phase 3: replay each chunk from its prefix, writing every C_t into its slot.
__global__ void k_cwrite(const int* __restrict__ tokens,
                         const float* __restrict__ eW1, const float* __restrict__ eb1,
                         const float* __restrict__ eW2, const float* __restrict__ eb2,
                         float* __restrict__ out) {
    __shared__ float4 gt[kV];
    build_gtable(eW1, eb1, eW2, eb2, gt);
    int gid = blockIdx.x * blockDim.x + threadIdx.x;   // 0 .. 16383
    int b = gid / kNC, c = gid % kNC;
    int base = b * kT + c * kCL;
    float4 p4 = *slotPF(out, gid);
    Quat W{p4.x, p4.y, p4.z, p4.w};
    #pragma unroll 4
    for (int i = 0; i < kCL; ++i) {
        float4 g4 = gt[tokens[base + i]];
        W = qnorm(qmul(W, Quat{g4.x, g4.y, g4.z, g4.w}));
        *slotC(out, base + i) = make_float4(W.w, W.x, W.y, W.z);
    }
}

// Phase 4: head. Lane t: read C from its slot, overwrite slot with 64 f32
// logits, write f32 sigma to the tail region.
__global__ __launch_bounds__(256) void k_head(const float* __restrict__ hW1,
                                              const float* __restrict__ hb1,
                                              const float* __restrict__ hW2,
                                              const float* __restrict__ hb2,
                                              float* __restrict__ out) {
    __shared__ float4 w1t[kH];      // [k] -> (hW1[0][k], hW1[1][k], hW1[2][k], hW1[3][k])
    __shared__ float  w2s[kH * kH]; // row-major [k][j], 16 KB
    __shared__ float  b1s[kH], b2s[kH];
    int tid = threadIdx.x;
    for (int i = tid; i < kH * kH; i += 256) w2s[i] = hW2[i];
    if (tid < kH) {
        w1t[tid] = make_float4(hW1[0*kH + tid], hW1[1*kH + tid],
                               hW1[2*kH + tid], hW1[3*kH + tid]);
        b1s[tid] = hb1[tid];
        b2s[tid] = hb2[tid];
    }
    __syncthreads();

    int t = blockIdx.x * 256 + tid;            // 0 .. BT-1
    float4 c4 = *slotC(out, t);                // (w,x,y,z)

    float acc[kH];
    #pragma unroll
    for (int j = 0; j < kH; ++j) acc[j] = b2s[j];

    for (int k = 0; k < kH; ++k) {
        float4 w1 = w1t[k];
        float pre = c4.x*w1.x + c4.y*w1.y + c4.z*w1.z + c4.w*w1.w + b1s[k];
        float h = gelu_exact(pre);
        const float4* w2r = reinterpret_cast<const float4*>(&w2s[k * kH]);
        #pragma unroll
        for (int j4 = 0; j4 < kH / 4; ++j4) {
            float4 v = w2r[j4];
            acc[j4*4+0] += h * v.x;
            acc[j4*4+1] += h * v.y;
            acc[j4*4+2] += h * v.z;
            acc[j4*4+3] += h * v.w;
        }
    }

    // 64 f32 logits = 256 B contiguous, 16x float4 stores (overwrites slot)
    float4* dst = reinterpret_cast<float4*>(out) + (size_t)t * 16;
    #pragma unroll
    for (int g = 0; g < 16; ++g)
        dst[g] = make_float4(acc[g*4+0], acc[g*4+1], acc[g*4+2], acc[g*4+3]);

    float sig = acosf(fminf(fabsf(c4.x), 1.0f - 1e-7f));
    out[(size_t)kBT * kH + t] = sig;
}

extern "C" void kernel_launch(void* const* d_in, const int* in_sizes, int n_in,
                              void* d_out, int out_size, void* d_ws, size_t ws_size,
                              hipStream_t stream) {
    const int*   tokens = (const int*)  d_in[0];
    const float* eW1    = (const float*)d_in[1];
    const float* eb1    = (const float*)d_in[2];
    const float* eW2    = (const float*)d_in[3];
    const float* eb2    = (const float*)d_in[4];
    const float* hW1    = (const float*)d_in[5];
    const float* hb1    = (const float*)d_in[6];
    const float* hW2    = (const float*)d_in[7];
    const float* hb2    = (const float*)d_in[8];
    float* out = (float*)d_out;     // float32 (proven R4->R5 bisection)
    (void)d_ws; (void)ws_size;

    k_chunkprod<<<kNChunksTotal / 256, 256, 0, stream>>>(tokens, eW1, eb1, eW2, eb2, out);
    k_prefix   <<<kB / 32,             256, 0, stream>>>(out);
    k_cwrite   <<<kNChunksTotal / 256, 256, 0, stream>>>(tokens, eW1, eb1, eW2, eb2, out);
    k_head     <<<kBT / 256,           256, 0, stream>>>(hW1, hb1, hW2, hb2, out);
}

// Round 7
// 203.499 us; speedup vs baseline: 1.4373x; 1.4373x over previous
//
#include <hip/hip_runtime.h>
#include <math.h>

// S3RNN: token->quaternion table -> per-row chunked scan (1 kernel) ->
// MFMA head (H = gelu(C@W1+b1) on the fly, logits = H@W2 via 16x16x32 bf16).
// Inputs fp32, d_out fp32 (proven by R0-R5 bisection). d_ws holds C_all
// (8 MB float4; R1/R2 bit-identical results prove ws is large enough).
namespace {
constexpr int kB   = 256;
constexpr int kT   = 2048;
constexpr int kH   = 64;
constexpr int kV   = 64;
constexpr int kNC  = 64;          // chunks per row
constexpr int kCL  = kT / kNC;    // 32 steps per chunk
constexpr int kBT  = kB * kT;     // 524288
constexpr int kEOS = 2;
constexpr size_t kSigOff = (size_t)kBT * kH;  // f32 offset of sigma region
}

typedef __attribute__((ext_vector_type(8))) short bf16x8;
typedef __attribute__((ext_vector_type(4))) float f32x4;

__device__ __forceinline__ unsigned short f2bf(float f) {
    unsigned u = __float_as_uint(f);
    unsigned r = 0x7FFFu + ((u >> 16) & 1u);
    return (unsigned short)((u + r) >> 16);
}

__device__ __forceinline__ float gelu_exact(float x) {
    return 0.5f * x * (1.0f + erff(x * 0.70710678118654752440f));
}

struct Quat { float w, x, y, z; };

__device__ __forceinline__ Quat qmul(Quat a, Quat b) {
    Quat r;
    r.w = a.w*b.w - a.x*b.x - a.y*b.y - a.z*b.z;
    r.x = a.w*b.x + a.x*b.w + a.y*b.z - a.z*b.y;
    r.y = a.w*b.y - a.x*b.z + a.y*b.w + a.z*b.x;
    r.z = a.w*b.z + a.x*b.y - a.y*b.x + a.z*b.w;
    return r;
}

__device__ __forceinline__ Quat qnorm(Quat a) {
    float n2 = a.w*a.w + a.x*a.x + a.y*a.y + a.z*a.z;
    float n  = fmaxf(sqrtf(n2), 1e-12f);
    float inv = 1.0f / n;
    return Quat{a.w*inv, a.x*inv, a.y*inv, a.z*inv};
}

// One block (64 threads) per row: gtable -> chunk products -> serial prefix
// -> replay, writing C_all (ws) and sigma (out tail).
__global__ __launch_bounds__(64) void k_scan(const int* __restrict__ tokens,
                                             const float* __restrict__ eW1, const float* __restrict__ eb1,
                                             const float* __restrict__ eW2, const float* __restrict__ eb2,
                                             float4* __restrict__ C_all,
                                             float* __restrict__ out) {
    __shared__ float4 gt[kV];
    __shared__ float4 cp[kNC];
    __shared__ float4 pf[kNC];
    int tid = threadIdx.x;
    int row = blockIdx.x;

    // g-table: entry tid
    {
        float a0 = 0.f, a1 = 0.f, a2 = 0.f, a3 = 0.f;
        const float* r = eW1 + tid * kH;
        for (int k = 0; k < kH; ++k) {
            float h = gelu_exact(r[k] + eb1[k]);
            a0 += h * eW2[k*4+0];
            a1 += h * eW2[k*4+1];
            a2 += h * eW2[k*4+2];
            a3 += h * eW2[k*4+3];
        }
        Quat g{a0 + eb2[0], a1 + eb2[1], a2 + eb2[2], a3 + eb2[3]};
        g = qnorm(g);
        if (tid == kEOS) g = Quat{1.f, 0.f, 0.f, 0.f};
        gt[tid] = make_float4(g.w, g.x, g.y, g.z);
    }
    __syncthreads();

    // chunk product for chunk tid
    int base = row * kT + tid * kCL;
    {
        Quat Q{1.f, 0.f, 0.f, 0.f};
        #pragma unroll 4
        for (int i = 0; i < kCL; ++i) {
            float4 g4 = gt[tokens[base + i]];
            Q = qnorm(qmul(Q, Quat{g4.x, g4.y, g4.z, g4.w}));
        }
        cp[tid] = make_float4(Q.w, Q.x, Q.y, Q.z);
    }
    __syncthreads();

    // exclusive prefix over 64 chunks (serial, thread 0)
    if (tid == 0) {
        Quat P{1.f, 0.f, 0.f, 0.f};
        for (int c = 0; c < kNC; ++c) {
            pf[c] = make_float4(P.w, P.x, P.y, P.z);
            float4 q4 = cp[c];
            P = qnorm(qmul(P, Quat{q4.x, q4.y, q4.z, q4.w}));
        }
    }
    __syncthreads();

    // replay chunk tid, writing C and sigma
    {
        float4 p4 = pf[tid];
        Quat W{p4.x, p4.y, p4.z, p4.w};
        #pragma unroll 4
        for (int i = 0; i < kCL; ++i) {
            float4 g4 = gt[tokens[base + i]];
            W = qnorm(qmul(W, Quat{g4.x, g4.y, g4.z, g4.w}));
            C_all[base + i] = make_float4(W.w, W.x, W.y, W.z);
            out[kSigOff + base + i] = acosf(fminf(fabsf(W.w), 1.0f - 1e-7f));
        }
    }
}

// MFMA head. Wave handles 8 M-tiles of 16 t's. W2 resident in B-frag regs
// (bf16), W1/b1 slices in regs, H computed fp32 -> bf16 A-frags.
// A layout: A[m=lane&15][k=quad*8+j]; B: B[k=quad*8+j][n=lane&15];
// D: row m=quad*4+reg, col n=lane&15.
__global__ __launch_bounds__(256) void k_head(const float4* __restrict__ C_all,
                                              const float* __restrict__ hW1,
                                              const float* __restrict__ hb1,
                                              const float* __restrict__ hW2,
                                              const float* __restrict__ hb2,
                                              float* __restrict__ out) {
    int lane = threadIdx.x & 63;
    int wave = threadIdx.x >> 6;
    int quad = lane >> 4;
    int col  = lane & 15;

    // per-lane W1 column slices + b1 for k = s*32 + quad*8 + j
    float w1r[2][4][8];
    float b1r[2][8];
    #pragma unroll
    for (int s = 0; s < 2; ++s) {
        int k0 = s*32 + quad*8;
        #pragma unroll
        for (int j = 0; j < 8; ++j) b1r[s][j] = hb1[k0 + j];
        #pragma unroll
        for (int i = 0; i < 4; ++i)
            #pragma unroll
            for (int j = 0; j < 8; ++j)
                w1r[s][i][j] = hW1[i*kH + k0 + j];
    }

    // B-frags: all of W2 as bf16, 4 n-tiles x 2 k-steps
    bf16x8 bfrag[4][2];
    #pragma unroll
    for (int nt = 0; nt < 4; ++nt)
        #pragma unroll
        for (int s = 0; s < 2; ++s) {
            int k0 = s*32 + quad*8;
            bf16x8 f;
            #pragma unroll
            for (int j = 0; j < 8; ++j)
                f[j] = (short)f2bf(hW2[(k0 + j)*kH + nt*16 + col]);
            bfrag[nt][s] = f;
        }

    float b2v[4];
    #pragma unroll
    for (int nt = 0; nt < 4; ++nt) b2v[nt] = hb2[nt*16 + col];

    int tile0 = blockIdx.x * 32 + wave * 8;   // 32 tiles/block, 8/wave
    for (int it = 0; it < 8; ++it) {
        int t0 = (tile0 + it) * 16;
        float4 c4 = C_all[t0 + col];          // (w,x,y,z), 4-way broadcast

        bf16x8 afrag[2];
        #pragma unroll
        for (int s = 0; s < 2; ++s) {
            bf16x8 f;
            #pragma unroll
            for (int j = 0; j < 8; ++j) {
                float pre = c4.x*w1r[s][0][j] + c4.y*w1r[s][1][j]
                          + c4.z*w1r[s][2][j] + c4.w*w1r[s][3][j] + b1r[s][j];
                f[j] = (short)f2bf(gelu_exact(pre));
            }
            afrag[s] = f;
        }

        f32x4 acc0 = {0.f,0.f,0.f,0.f}, acc1 = {0.f,0.f,0.f,0.f};
        f32x4 acc2 = {0.f,0.f,0.f,0.f}, acc3 = {0.f,0.f,0.f,0.f};
        acc0 = __builtin_amdgcn_mfma_f32_16x16x32_bf16(afrag[0], bfrag[0][0], acc0, 0,0,0);
        acc0 = __builtin_amdgcn_mfma_f32_16x16x32_bf16(afrag[1], bfrag[0][1], acc0, 0,0,0);
        acc1 = __builtin_amdgcn_mfma_f32_16x16x32_bf16(afrag[0], bfrag[1][0], acc1, 0,0,0);
        acc1 = __builtin_amdgcn_mfma_f32_16x16x32_bf16(afrag[1], bfrag[1][1], acc1, 0,0,0);
        acc2 = __builtin_amdgcn_mfma_f32_16x16x32_bf16(afrag[0], bfrag[2][0], acc2, 0,0,0);
        acc2 = __builtin_amdgcn_mfma_f32_16x16x32_bf16(afrag[1], bfrag[2][1], acc2, 0,0,0);
        acc3 = __builtin_amdgcn_mfma_f32_16x16x32_bf16(afrag[0], bfrag[3][0], acc3, 0,0,0);
        acc3 = __builtin_amdgcn_mfma_f32_16x16x32_bf16(afrag[1], bfrag[3][1], acc3, 0,0,0);

        // epilogue: D[row=quad*4+r][col], add b2, store f32
        #pragma unroll
        for (int r = 0; r < 4; ++r) {
            size_t rowoff = (size_t)(t0 + quad*4 + r) * kH + col;
            out[rowoff +  0] = acc0[r] + b2v[0];
            out[rowoff + 16] = acc1[r] + b2v[1];
            out[rowoff + 32] = acc2[r] + b2v[2];
            out[rowoff + 48] = acc3[r] + b2v[3];
        }
    }
}

extern "C" void kernel_launch(void* const* d_in, const int* in_sizes, int n_in,
                              void* d_out, int out_size, void* d_ws, size_t ws_size,
                              hipStream_t stream) {
    const int*   tokens = (const int*)  d_in[0];
    const float* eW1    = (const float*)d_in[1];
    const float* eb1    = (const float*)d_in[2];
    const float* eW2    = (const float*)d_in[3];
    const float* eb2    = (const float*)d_in[4];
    const float* hW1    = (const float*)d_in[5];
    const float* hb1    = (const float*)d_in[6];
    const float* hW2    = (const float*)d_in[7];
    const float* hb2    = (const float*)d_in[8];
    float* out = (float*)d_out;
    float4* C_all = (float4*)d_ws;   // 524288 * 16 B = 8 MB

    k_scan<<<kB, 64, 0, stream>>>(tokens, eW1, eb1, eW2, eb2, C_all, out);
    k_head<<<kBT / 512, 256, 0, stream>>>(C_all, hW1, hb1, hW2, hb2, out);
}